// Round 9
// baseline (940.012 us; speedup 1.0000x reference)
//
#include <hip/hip_runtime.h>
#include <math.h>

#define B_  8
#define S_  16
#define H_  32
#define W_  32
#define E_  128
#define NH_ 8
#define HD_ 16
#define HW_ (H_*W_)            // 1024
#define NTOK (B_*S_*H_*W_)     // 131072

typedef __attribute__((ext_vector_type(8))) short short8;
typedef __attribute__((ext_vector_type(4))) short short4v;
typedef __attribute__((ext_vector_type(4))) float floatx4;

__device__ __forceinline__ float sigf(float x){
    return 1.f/(1.f+__expf(-x));
}
__device__ __forceinline__ float tanh_fast(float x){
    x = fminf(fmaxf(x, -15.f), 15.f);
    float e = __expf(2.f*x);
    return (e-1.f)/(e+1.f);
}
__device__ __forceinline__ unsigned short f2bf(float f){
    unsigned int u = __float_as_uint(f);
    u = (u + 0x7fffu + ((u >> 16) & 1u)) >> 16;   // RNE
    return (unsigned short)u;
}
__device__ __forceinline__ float bf2f(unsigned short h){
    return __uint_as_float(((unsigned int)h) << 16);
}

// ---------------------------------------------------------------------------
// W_proj (128x128 fp32) -> split-bf16 B' fragments for K=384 GEMM.
__global__ __launch_bounds__(256)
void k_pack_wproj(const float* __restrict__ Wp, short* __restrict__ Wpp){
    int p = blockIdx.x*256 + threadIdx.x;    // 6144 packets
    int L = p & 63;
    int idx = p >> 6;                        // nt*12 + kb
    int nt = idx / 12, kb = idx - nt*12;
    int n = nt*16 + (L & 15);
    int kr = (kb & 3)*32 + (L >> 4)*8;
    bool lo = (kb >= 8);
    short8 v;
    #pragma unroll
    for (int j=0;j<8;j++){
        float wv = Wp[(kr+j)*128 + n];
        unsigned short h = f2bf(wv);
        v[j] = lo ? (short)f2bf(wv - bf2f(h)) : (short)h;
    }
    *(short8*)&Wpp[(long)p*8] = v;
}

// ---------------------------------------------------------------------------
// X = LayerNorm(silu(inputs @ W_proj)) via split-bf16 MFMA (fp32-accurate).
// Wave = 4 m-tiles x 2 n-tiles (B per wave 24 KB); LN row-sums cross waves
// via LDS red[] + barrier.
__global__ __launch_bounds__(256,4)
void k_proj_ln_mfma(const float* __restrict__ in, const short* __restrict__ Wpp,
                    const float* __restrict__ gamma, const float* __restrict__ beta,
                    float* __restrict__ X){
    __shared__ short As[64*264];             // 33,792 B
    __shared__ float red[4][64][2];          //  2,048 B
    int tid = threadIdx.x;
    int w = tid >> 6, L = tid & 63;
    int quad = L >> 4, lm = L & 15;
    long r0 = (long)blockIdx.x * 64;

    // stage: 64 rows x 128 f32 -> split bf16 (coalesced float4 loads)
    {
        int c = (tid & 31)*4;
        int rbase = tid >> 5;
        #pragma unroll
        for (int rr=0; rr<8; rr++){
            int r = rr*8 + rbase;
            float4 v = *(const float4*)&in[(r0 + r)*128 + c];
            short4v hv, lv;
            unsigned short h;
            h = f2bf(v.x); hv[0]=(short)h; lv[0]=(short)f2bf(v.x - bf2f(h));
            h = f2bf(v.y); hv[1]=(short)h; lv[1]=(short)f2bf(v.y - bf2f(h));
            h = f2bf(v.z); hv[2]=(short)h; lv[2]=(short)f2bf(v.z - bf2f(h));
            h = f2bf(v.w); hv[3]=(short)h; lv[3]=(short)f2bf(v.w - bf2f(h));
            *(short4v*)&As[r*264 + c] = hv;
            *(short4v*)&As[r*264 + 128 + c] = lv;
        }
    }
    __syncthreads();

    floatx4 acc[4][2];
    #pragma unroll
    for (int mtl=0;mtl<4;mtl++)
        #pragma unroll
        for (int nti=0;nti<2;nti++)
            acc[mtl][nti] = (floatx4){0.f,0.f,0.f,0.f};
    const short8* Bp8 = (const short8*)Wpp;
    #pragma unroll
    for (int kb=0; kb<12; kb++){
        int off = (kb<4) ? kb*32 : ((kb<8) ? 128+(kb-4)*32 : (kb-8)*32);
        short8 af[4];
        #pragma unroll
        for (int mtl=0;mtl<4;mtl++)
            af[mtl] = *(const short8*)&As[(mtl*16+lm)*264 + off + quad*8];
        #pragma unroll
        for (int nti=0;nti<2;nti++){
            short8 bf = Bp8[((2*w+nti)*12+kb)*64 + L];
            #pragma unroll
            for (int mtl=0;mtl<4;mtl++)
                acc[mtl][nti] = __builtin_amdgcn_mfma_f32_16x16x32_bf16(af[mtl], bf, acc[mtl][nti], 0,0,0);
        }
    }

    // fused silu + LayerNorm epilogue (cross-wave row reduction).
    #pragma unroll
    for (int mtl=0;mtl<4;mtl++){
        float p1[4]={0,0,0,0}, p2[4]={0,0,0,0};
        #pragma unroll
        for (int nti=0;nti<2;nti++)
            #pragma unroll
            for (int r=0;r<4;r++){
                float a = acc[mtl][nti][r];
                float si = a*sigf(a);             // silu
                acc[mtl][nti][r] = si;
                p1[r] += si; p2[r] += si*si;
            }
        #pragma unroll
        for (int d=1; d<16; d<<=1)
            #pragma unroll
            for (int r=0;r<4;r++){
                p1[r] += __shfl_xor(p1[r], d);
                p2[r] += __shfl_xor(p2[r], d);
            }
        if (lm == 0){
            #pragma unroll
            for (int r=0;r<4;r++){
                int row = mtl*16 + quad*4 + r;
                red[w][row][0] = p1[r];
                red[w][row][1] = p2[r];
            }
        }
    }
    __syncthreads();
    float g[2], bb[2];
    #pragma unroll
    for (int nti=0;nti<2;nti++){
        g[nti]  = gamma[(2*w+nti)*16 + lm];
        bb[nti] = beta [(2*w+nti)*16 + lm];
    }
    #pragma unroll
    for (int mtl=0;mtl<4;mtl++){
        #pragma unroll
        for (int r=0;r<4;r++){
            int row = mtl*16 + quad*4 + r;
            float s1 = red[0][row][0] + red[1][row][0] + red[2][row][0] + red[3][row][0];
            float s2 = red[0][row][1] + red[1][row][1] + red[2][row][1] + red[3][row][1];
            float mu  = s1 * (1.f/128.f);
            float var = s2 * (1.f/128.f) - mu*mu;
            float rs  = rsqrtf(var + 1e-5f);
            #pragma unroll
            for (int nti=0;nti<2;nti++)
                X[(r0+row)*128 + (2*w+nti)*16 + lm] = (acc[mtl][nti][r]-mu)*rs*g[nti] + bb[nti];
        }
    }
}

// ---------------------------------------------------------------------------
// W_in (128x384) -> bf16 B-fragment packets.
__global__ __launch_bounds__(256)
void k_pack_win(const float* __restrict__ Win, short* __restrict__ Winp){
    int p = blockIdx.x*256 + threadIdx.x;    // 6144 packets
    int L = p & 63;
    int idx = p >> 6;                        // nt*4+kc
    int nt = idx >> 2, kc = idx & 3;
    int n = nt*16 + (L & 15);
    int k0 = kc*32 + (L >> 4)*8;
    short8 v;
    #pragma unroll
    for (int j=0;j<8;j++) v[j] = (short)f2bf(Win[(k0+j)*384 + n]);
    *(short8*)&Winp[(long)p*8] = v;
}

// ---------------------------------------------------------------------------
// W_out (128x128) -> per-head zero-padded B packets.
__global__ __launch_bounds__(256)
void k_pack_wout(const float* __restrict__ Wout, short* __restrict__ Woutp){
    int p = blockIdx.x*256 + threadIdx.x;    // 4096 packets
    int L = p & 63;
    int idx = p >> 6;                        // h*8+nt
    int h = idx >> 3, nt = idx & 7;
    int n = nt*16 + (L & 15);
    int k0 = (L >> 4)*8;
    short8 v;
    #pragma unroll
    for (int j=0;j<8;j++){
        int k = k0 + j;
        v[j] = (k < 16) ? (short)f2bf(Wout[(h*16+k)*128 + n]) : (short)0;
    }
    *(short8*)&Woutp[(long)p*8] = v;
}

// ---------------------------------------------------------------------------
// Fused MFMA attention (R6/R8 best: 4 sites, 32 KB LDS, 77 us, 41% occ).
__global__ __launch_bounds__(256,5)
void k_attn_mfma(const float* __restrict__ X, const short* __restrict__ Winp,
                 const short* __restrict__ Woutp, const float* __restrict__ resid,
                 float* __restrict__ Y){
    __shared__ short lds[16000];             // 32,000 B
    const int XO=0;                          // X tile  [64][136]
    const int QO=8704;                       // Q plain [64][24]
    const int KO=10240;                      // K plain [64][24]
    const int VO=11776;                      // V^T     [16][72] (cols = m)
    const int PO=12928;                      // P plain [64][24]
    const int AOO=14464;                     // ao      [64][24]
    int tid = threadIdx.x;
    int w = tid >> 6, L = tid & 63;
    int quad = L >> 4, lm = L & 15;
    int b = blockIdx.x >> 8, tile = blockIdx.x & 255;
    int hw0 = tile * 4;
    int hw = hw0 + w;                        // this wave's site

    // phase 1: wave-local X rows w*16..w*16+15 (site w), fp32->bf16
    {
        int cq = L & 31, rh = L >> 5;
        for (int p=0; p<8; p++){
            int m = w*16 + p*2 + rh;
            int s = m & 15;
            float4 v = *(const float4*)&X[((((long)b*16 + s)*1024) + hw)*128 + cq*4];
            short4v hv;
            hv[0]=(short)f2bf(v.x); hv[1]=(short)f2bf(v.y);
            hv[2]=(short)f2bf(v.z); hv[3]=(short)f2bf(v.w);
            *(short4v*)&lds[XO + m*136 + cq*4] = hv;
        }
    }

    floatx4 Oa[8];
    #pragma unroll
    for (int nt=0;nt<8;nt++) Oa[nt] = (floatx4){0.f,0.f,0.f,0.f};

    const floatx4 zc = (floatx4){0.f,0.f,0.f,0.f};
    const short8 z8 = {0,0,0,0,0,0,0,0};
    int m0 = w*16;

    for (int h=0; h<8; h++){
        // ---- phase 2: QKV GEMM for n-tiles {3h, 3h+1, 3h+2} = q,k,v of head h
        floatx4 qacc[3];
        #pragma unroll
        for (int t=0;t<3;t++) qacc[t] = zc;
        #pragma unroll
        for (int kc=0;kc<4;kc++){
            short8 af = *(const short8*)&lds[XO + (m0+lm)*136 + kc*32 + quad*8];
            #pragma unroll
            for (int t=0;t<3;t++){
                int nt = 3*h + t;
                short8 bf = *(const short8*)&Winp[(long)((nt*4+kc)*64 + L)*8];
                qacc[t] = __builtin_amdgcn_mfma_f32_16x16x32_bf16(af, bf, qacc[t], 0,0,0);
            }
        }
        // epilogue: Q,K -> plain [m][d]; V -> V^T [d][m]
        #pragma unroll
        for (int r=0;r<4;r++){
            lds[QO + (m0+quad*4+r)*24 + lm] = (short)f2bf(qacc[0][r]);
            lds[KO + (m0+quad*4+r)*24 + lm] = (short)f2bf(qacc[1][r]);
        }
        {
            short4v vv;
            #pragma unroll
            for (int r=0;r<4;r++) vv[r] = (short)f2bf(qacc[2][r]);
            *(short4v*)&lds[VO + lm*72 + m0 + quad*4] = vv;
        }

        // ---- phase 3: per-site scores -> softmax -> PV ----
        {
            short8 qf = z8, kf = z8;
            if (quad < 2){
                qf = *(const short8*)&lds[QO + (m0+lm)*24 + quad*8];
                kf = *(const short8*)&lds[KO + (m0+lm)*24 + quad*8];
            }
            floatx4 scv = __builtin_amdgcn_mfma_f32_16x16x32_bf16(qf, kf, zc, 0,0,0);
            float pv[4], mr[4];
            #pragma unroll
            for (int r=0;r<4;r++){
                int si = quad*4 + r;
                pv[r] = scv[r]*0.25f + (lm <= si ? 1.0f : -1000.0f);
                mr[r] = pv[r];
            }
            #pragma unroll
            for (int d=1; d<16; d<<=1)
                #pragma unroll
                for (int r=0;r<4;r++) mr[r] = fmaxf(mr[r], __shfl_xor(mr[r], d));
            float ex[4], sm[4];
            #pragma unroll
            for (int r=0;r<4;r++){ ex[r] = __expf(pv[r]-mr[r]); sm[r] = ex[r]; }
            #pragma unroll
            for (int d=1; d<16; d<<=1)
                #pragma unroll
                for (int r=0;r<4;r++) sm[r] += __shfl_xor(sm[r], d);
            #pragma unroll
            for (int r=0;r<4;r++)
                lds[PO + (m0+quad*4+r)*24 + lm] = (short)f2bf(ex[r]/sm[r]);

            short8 pf = z8, vf = z8;
            if (quad < 2){
                pf = *(const short8*)&lds[PO + (m0+lm)*24 + quad*8];
                vf = *(const short8*)&lds[VO + lm*72 + m0 + quad*8];
            }
            floatx4 aov = __builtin_amdgcn_mfma_f32_16x16x32_bf16(pf, vf, zc, 0,0,0);
            #pragma unroll
            for (int r=0;r<4;r++)
                lds[AOO + (m0+quad*4+r)*24 + lm] = (short)f2bf(aov[r]);
        }

        // ---- phase 4: O += ao_h @ Wout[h-rows] ----
        {
            short8 aof = z8;
            if (quad < 2)
                aof = *(const short8*)&lds[AOO + (m0+lm)*24 + quad*8];
            #pragma unroll
            for (int nt=0;nt<8;nt++){
                short8 wf = *(const short8*)&Woutp[(long)((h*8+nt)*64 + L)*8];
                Oa[nt] = __builtin_amdgcn_mfma_f32_16x16x32_bf16(aof, wf, Oa[nt], 0,0,0);
            }
        }
    }

    // epilogue: O + residual -> Y (in place over X rows this block loaded)
    #pragma unroll
    for (int nt=0;nt<8;nt++){
        int n = nt*16 + lm;
        #pragma unroll
        for (int r=0;r<4;r++){
            int s = quad*4 + r;
            long addr = (((long)b*16 + s)*1024 + hw)*128 + n;
            Y[addr] = Oa[nt][r] + resid[addr];
        }
    }
}

// ---------------------------------------------------------------------------
// Weights -> B-fragment packets, bf16 (conv GEMM).
__global__ __launch_bounds__(256)
void k_pack_w(const float* __restrict__ ck, short* __restrict__ Bp){
    int p = blockIdx.x*256 + threadIdx.x;     // 147456 exact
    int L = p & 63;
    int nt = (p >> 6) & 31;
    int c32 = (p >> 11) & 7;
    int tap = p >> 14;
    int oc = nt*16 + (L & 15);
    int kq = L >> 4;
    short8 v;
    #pragma unroll
    for (int j=0;j<8;j++){
        int ic = c32*32 + kq*8 + j;
        v[j] = (short)f2bf(ck[(oc*256+ic)*9 + tap]);
    }
    *(short8*)&Bp[(long)p*8] = v;
}

// ---------------------------------------------------------------------------
// Pack X slice s (fp32) -> bf16 x-half of xh[row][0:128]; zero h-half at s==0
// (used once for s=0; the fused conv+lstm kernel packs slices 1..15 inline)
__global__ __launch_bounds__(256)
void k_pack_x(const float* __restrict__ X, short* __restrict__ xh, int s, int zero_h){
    int idx = blockIdx.x*256 + threadIdx.x;   // 131072
    int row = idx >> 4;
    int ch = (idx & 15) * 8;
    int b = row >> 10, hw = row & 1023;
    const float* src = X + (((long)(b*16+s)*1024 + hw)*128 + ch);
    float4 a = *(const float4*)src;
    float4 c = *(const float4*)(src+4);
    short8 v;
    v[0]=(short)f2bf(a.x); v[1]=(short)f2bf(a.y); v[2]=(short)f2bf(a.z); v[3]=(short)f2bf(a.w);
    v[4]=(short)f2bf(c.x); v[5]=(short)f2bf(c.y); v[6]=(short)f2bf(c.z); v[7]=(short)f2bf(c.w);
    *(short8*)&xh[(long)row*256 + ch] = v;
    if (zero_h){
        short8 z = {0,0,0,0,0,0,0,0};
        *(short8*)&xh[(long)row*256 + 128 + ch] = z;
    }
}

// ---------------------------------------------------------------------------
// Fused implicit-im2col conv GEMM + LSTM pointwise (R9).
// The gbuf round-trip and the separate k_lstm dispatch are eliminated: each
// wave's 4 n-tiles are ONE PER GATE at the same channel sub-block
// (nt(q) = q*8 + Nblk*2 + wn -> n = q*128 + ch), so after the K-loop each
// lane holds gates i,f,o,g for its 8 (row,ch) outputs in registers and the
// LSTM pointwise runs inline: update cbuf, write hn to X slice s, and pack
// xh for step s+1 into the OTHER xh buffer (double-buffered: conv_s reads
// xh_in, writes xh_out; no cross-block race). Conv accumulation order
// (tap,sic,c2) and the f32 gate path are unchanged -> bit-identical output.
// Mtile=128 (4 image rows), grid 64x4=256, 512 thr, halo staged once,
// barrier-free K-loop, Nblk=blockIdx&3 XCD-aligned.
__global__ __launch_bounds__(512,2)
void k_conv_lstm(const short* __restrict__ xh_in, const short* __restrict__ Bp,
                 float* __restrict__ cbuf, float* __restrict__ X,
                 short* __restrict__ xh_out, int s){
    __shared__ short As[6*34*264];           // 107,712 B
    int tid = threadIdx.x;
    int Nblk = blockIdx.x & 3, g = blockIdx.x >> 2;      // g 0..63
    int b = g >> 3, y0 = (g & 7)*4;
    int w = tid >> 6, L = tid & 63;
    int quad = L >> 4, lm = L & 15;
    int wm = w >> 1, wn = w & 1;             // wave -> (m-row, n-half)

    // ---- stage A halo: rows y0-1..y0+4, x -1..32, ch 0..255 (zero-padded)
    const short8 z8 = {0,0,0,0,0,0,0,0};
    {
        short8 vs[13];
        #pragma unroll
        for (int i=0; i<13; i++){
            int pidx = i*512 + tid;
            short8 v = z8;
            if (pidx < 6528){
                int cb  = pidx & 31;             // 8-ch granule
                int pos = pidx >> 5;             // row*34 + xp
                int row = pos / 34;
                int xp  = pos - row*34;
                int yy = y0 - 1 + row, xx = xp - 1;
                if (yy>=0 && yy<32 && xx>=0 && xx<32)
                    v = *(const short8*)&xh_in[(((long)(b*32+yy)*32+xx)<<8) + cb*8];
            }
            vs[i] = v;
        }
        #pragma unroll
        for (int i=0; i<13; i++){
            int pidx = i*512 + tid;
            if (pidx < 6528){
                int cb  = pidx & 31;
                int pos = pidx >> 5;
                *(short8*)&As[pos*264 + cb*8] = vs[i];
            }
        }
    }
    __syncthreads();

    floatx4 acc[2][4];
    #pragma unroll
    for (int mtl=0;mtl<2;mtl++)
        #pragma unroll
        for (int q=0;q<4;q++)
            acc[mtl][q] = (floatx4){0.f,0.f,0.f,0.f};

    const short8* Bp8 = (const short8*)Bp;

    for (int tap=0; tap<9; tap++){
        int dy = tap/3 - 1, dx = tap - (tap/3)*3 - 1;
        // wave wm owns image row ys=wm (of 4); m-tiles wm*2+mtl, x = mtl*16+lm
        int abase[2];
        #pragma unroll
        for (int mtl=0;mtl<2;mtl++){
            int x = mtl*16 + lm;
            abase[mtl] = (((wm+dy+1)*34) + x + dx + 1)*264 + quad*8;
        }
        #pragma unroll
        for (int sic=0; sic<4; sic++){
            #pragma unroll
            for (int c2=0; c2<2; c2++){
                short8 bfr[4];
                #pragma unroll
                for (int q=0;q<4;q++)
                    bfr[q] = Bp8[((tap*8 + sic*2 + c2)*32 + q*8 + Nblk*2 + wn)*64 + L];
                #pragma unroll
                for (int mtl=0;mtl<2;mtl++){
                    short8 afr = *(const short8*)&As[abase[mtl] + sic*64 + c2*32];
                    #pragma unroll
                    for (int q=0;q<4;q++)
                        acc[mtl][q] = __builtin_amdgcn_mfma_f32_16x16x32_bf16(afr, bfr[q], acc[mtl][q], 0,0,0);
                }
            }
        }
    }

    // ---- fused LSTM pointwise epilogue ----
    // lane holds gates q=0..3 (i,f,o,g) for rows (wm*32+mtl*16+quad*4+r) and
    // channel ch; c_prev from cbuf; write cn, hn->X slice s, pack xh_out.
    int ch = Nblk*32 + wn*16 + lm;
    #pragma unroll
    for (int mtl=0;mtl<2;mtl++){
        #pragma unroll
        for (int r=0;r<4;r++){
            long row = (long)g*128 + wm*32 + mtl*16 + quad*4 + r;   // b*1024+hw
            float co = (s == 0) ? 0.f : cbuf[row*128 + ch];
            float gi = acc[mtl][0][r], gf = acc[mtl][1][r];
            float go = acc[mtl][2][r], gg = acc[mtl][3][r];
            float cn = sigf(gf)*co + sigf(gi)*tanh_fast(gg);
            float hn = sigf(go)*tanh_fast(cn);
            cbuf[row*128 + ch] = cn;
            int b2 = (int)(row >> 10), hw = (int)(row & 1023);
            long xoff = (((long)(b2*16+s)*1024 + hw)*128) + ch;
            X[xoff] = hn;
            xh_out[row*256 + 128 + ch] = (short)f2bf(hn);
            if (s < 15){
                long x2 = (((long)(b2*16+s+1)*1024 + hw)*128) + ch;
                xh_out[row*256 + ch] = (short)f2bf(X[x2]);
            }
        }
    }
}

// ---------------------------------------------------------------------------
extern "C" void kernel_launch(void* const* d_in, const int* in_sizes, int n_in,
                              void* d_out, int out_size, void* d_ws, size_t ws_size,
                              hipStream_t stream){
    const float* inputs = (const float*)d_in[0];
    const float* Wp     = (const float*)d_in[1];
    const float* gamma  = (const float*)d_in[2];
    const float* beta   = (const float*)d_in[3];
    const float* Win    = (const float*)d_in[4];
    const float* Wout   = (const float*)d_in[5];
    const float* ck     = (const float*)d_in[6];
    float* X = (float*)d_out;

    char* ws = (char*)d_ws;
    const size_t szB    = 147456ull*16;        // 2,359,296
    const size_t szXH   = 8192ull*256*2;       // 4,194,304 (each buffer)
    const size_t szC    = 8192ull*128*4;       // 4,194,304
    const size_t szWin  = 6144ull*16;          //    98,304
    const size_t szWout = 4096ull*16;          //    65,536
    short* Bp    = (short*)(ws);
    short* xh0   = (short*)(ws + szB);
    float* cbuf  = (float*)(ws + szB + szXH);
    short* Winp  = (short*)(ws + szB + szXH + szC);
    short* Woutp = (short*)(ws + szB + szXH + szC + szWin);
    short* xh1   = (short*)(ws + szB + szXH + szC + szWin + szWout);
    short* Wprojp= (short*)(ws + szB + szXH + szC + szWin + szWout + szXH);
    // total = 15.2 MB (gbuf eliminated; well under previous requirement)

    k_pack_w<<<576, 256, 0, stream>>>(ck, Bp);
    k_pack_win<<<24, 256, 0, stream>>>(Win, Winp);
    k_pack_wout<<<16, 256, 0, stream>>>(Wout, Woutp);
    k_pack_wproj<<<24, 256, 0, stream>>>(Wp, Wprojp);
    k_proj_ln_mfma<<<NTOK/64, 256, 0, stream>>>(inputs, Wprojp, gamma, beta, X);
    k_attn_mfma<<<2048, 256, 0, stream>>>(X, Winp, Woutp, inputs, X);  // in-place
    k_pack_x<<<512, 256, 0, stream>>>(X, xh0, 0, 1);

    for (int s=0; s<16; s++){
        const short* xin = (s & 1) ? xh1 : xh0;
        short*       xout= (s & 1) ? xh0 : xh1;
        k_conv_lstm<<<256, 512, 0, stream>>>(xin, Bp, cbuf, X, xout, s);
    }
}

// Round 10
// 927.712 us; speedup vs baseline: 1.0133x; 1.0133x over previous
//
#include <hip/hip_runtime.h>
#include <math.h>

#define B_  8
#define S_  16
#define H_  32
#define W_  32
#define E_  128
#define NH_ 8
#define HD_ 16
#define HW_ (H_*W_)            // 1024
#define NTOK (B_*S_*H_*W_)     // 131072

typedef __attribute__((ext_vector_type(8))) short short8;
typedef __attribute__((ext_vector_type(4))) short short4v;
typedef __attribute__((ext_vector_type(4))) float floatx4;

__device__ __forceinline__ float sigf(float x){
    return 1.f/(1.f+__expf(-x));
}
__device__ __forceinline__ float tanh_fast(float x){
    x = fminf(fmaxf(x, -15.f), 15.f);
    float e = __expf(2.f*x);
    return (e-1.f)/(e+1.f);
}
__device__ __forceinline__ unsigned short f2bf(float f){
    unsigned int u = __float_as_uint(f);
    u = (u + 0x7fffu + ((u >> 16) & 1u)) >> 16;   // RNE
    return (unsigned short)u;
}
__device__ __forceinline__ float bf2f(unsigned short h){
    return __uint_as_float(((unsigned int)h) << 16);
}

// ---------------------------------------------------------------------------
// W_proj (128x128 fp32) -> split-bf16 B' fragments for K=384 GEMM.
__global__ __launch_bounds__(256)
void k_pack_wproj(const float* __restrict__ Wp, short* __restrict__ Wpp){
    int p = blockIdx.x*256 + threadIdx.x;    // 6144 packets
    int L = p & 63;
    int idx = p >> 6;                        // nt*12 + kb
    int nt = idx / 12, kb = idx - nt*12;
    int n = nt*16 + (L & 15);
    int kr = (kb & 3)*32 + (L >> 4)*8;
    bool lo = (kb >= 8);
    short8 v;
    #pragma unroll
    for (int j=0;j<8;j++){
        float wv = Wp[(kr+j)*128 + n];
        unsigned short h = f2bf(wv);
        v[j] = lo ? (short)f2bf(wv - bf2f(h)) : (short)h;
    }
    *(short8*)&Wpp[(long)p*8] = v;
}

// ---------------------------------------------------------------------------
// X = LayerNorm(silu(inputs @ W_proj)) via split-bf16 MFMA (fp32-accurate).
// Wave = 4 m-tiles x 2 n-tiles (B per wave 24 KB); LN row-sums cross waves
// via LDS red[] + barrier.
__global__ __launch_bounds__(256,4)
void k_proj_ln_mfma(const float* __restrict__ in, const short* __restrict__ Wpp,
                    const float* __restrict__ gamma, const float* __restrict__ beta,
                    float* __restrict__ X){
    __shared__ short As[64*264];             // 33,792 B
    __shared__ float red[4][64][2];          //  2,048 B
    int tid = threadIdx.x;
    int w = tid >> 6, L = tid & 63;
    int quad = L >> 4, lm = L & 15;
    long r0 = (long)blockIdx.x * 64;

    // stage: 64 rows x 128 f32 -> split bf16 (coalesced float4 loads)
    {
        int c = (tid & 31)*4;
        int rbase = tid >> 5;
        #pragma unroll
        for (int rr=0; rr<8; rr++){
            int r = rr*8 + rbase;
            float4 v = *(const float4*)&in[(r0 + r)*128 + c];
            short4v hv, lv;
            unsigned short h;
            h = f2bf(v.x); hv[0]=(short)h; lv[0]=(short)f2bf(v.x - bf2f(h));
            h = f2bf(v.y); hv[1]=(short)h; lv[1]=(short)f2bf(v.y - bf2f(h));
            h = f2bf(v.z); hv[2]=(short)h; lv[2]=(short)f2bf(v.z - bf2f(h));
            h = f2bf(v.w); hv[3]=(short)h; lv[3]=(short)f2bf(v.w - bf2f(h));
            *(short4v*)&As[r*264 + c] = hv;
            *(short4v*)&As[r*264 + 128 + c] = lv;
        }
    }
    __syncthreads();

    floatx4 acc[4][2];
    #pragma unroll
    for (int mtl=0;mtl<4;mtl++)
        #pragma unroll
        for (int nti=0;nti<2;nti++)
            acc[mtl][nti] = (floatx4){0.f,0.f,0.f,0.f};
    const short8* Bp8 = (const short8*)Wpp;
    #pragma unroll
    for (int kb=0; kb<12; kb++){
        int off = (kb<4) ? kb*32 : ((kb<8) ? 128+(kb-4)*32 : (kb-8)*32);
        short8 af[4];
        #pragma unroll
        for (int mtl=0;mtl<4;mtl++)
            af[mtl] = *(const short8*)&As[(mtl*16+lm)*264 + off + quad*8];
        #pragma unroll
        for (int nti=0;nti<2;nti++){
            short8 bf = Bp8[((2*w+nti)*12+kb)*64 + L];
            #pragma unroll
            for (int mtl=0;mtl<4;mtl++)
                acc[mtl][nti] = __builtin_amdgcn_mfma_f32_16x16x32_bf16(af[mtl], bf, acc[mtl][nti], 0,0,0);
        }
    }

    // fused silu + LayerNorm epilogue (cross-wave row reduction).
    #pragma unroll
    for (int mtl=0;mtl<4;mtl++){
        float p1[4]={0,0,0,0}, p2[4]={0,0,0,0};
        #pragma unroll
        for (int nti=0;nti<2;nti++)
            #pragma unroll
            for (int r=0;r<4;r++){
                float a = acc[mtl][nti][r];
                float si = a*sigf(a);             // silu
                acc[mtl][nti][r] = si;
                p1[r] += si; p2[r] += si*si;
            }
        #pragma unroll
        for (int d=1; d<16; d<<=1)
            #pragma unroll
            for (int r=0;r<4;r++){
                p1[r] += __shfl_xor(p1[r], d);
                p2[r] += __shfl_xor(p2[r], d);
            }
        if (lm == 0){
            #pragma unroll
            for (int r=0;r<4;r++){
                int row = mtl*16 + quad*4 + r;
                red[w][row][0] = p1[r];
                red[w][row][1] = p2[r];
            }
        }
    }
    __syncthreads();
    float g[2], bb[2];
    #pragma unroll
    for (int nti=0;nti<2;nti++){
        g[nti]  = gamma[(2*w+nti)*16 + lm];
        bb[nti] = beta [(2*w+nti)*16 + lm];
    }
    #pragma unroll
    for (int mtl=0;mtl<4;mtl++){
        #pragma unroll
        for (int r=0;r<4;r++){
            int row = mtl*16 + quad*4 + r;
            float s1 = red[0][row][0] + red[1][row][0] + red[2][row][0] + red[3][row][0];
            float s2 = red[0][row][1] + red[1][row][1] + red[2][row][1] + red[3][row][1];
            float mu  = s1 * (1.f/128.f);
            float var = s2 * (1.f/128.f) - mu*mu;
            float rs  = rsqrtf(var + 1e-5f);
            #pragma unroll
            for (int nti=0;nti<2;nti++)
                X[(r0+row)*128 + (2*w+nti)*16 + lm] = (acc[mtl][nti][r]-mu)*rs*g[nti] + bb[nti];
        }
    }
}

// ---------------------------------------------------------------------------
// W_in (128x384) -> bf16 B-fragment packets.
__global__ __launch_bounds__(256)
void k_pack_win(const float* __restrict__ Win, short* __restrict__ Winp){
    int p = blockIdx.x*256 + threadIdx.x;    // 6144 packets
    int L = p & 63;
    int idx = p >> 6;                        // nt*4+kc
    int nt = idx >> 2, kc = idx & 3;
    int n = nt*16 + (L & 15);
    int k0 = kc*32 + (L >> 4)*8;
    short8 v;
    #pragma unroll
    for (int j=0;j<8;j++) v[j] = (short)f2bf(Win[(k0+j)*384 + n]);
    *(short8*)&Winp[(long)p*8] = v;
}

// ---------------------------------------------------------------------------
// W_out (128x128) -> per-head zero-padded B packets.
__global__ __launch_bounds__(256)
void k_pack_wout(const float* __restrict__ Wout, short* __restrict__ Woutp){
    int p = blockIdx.x*256 + threadIdx.x;    // 4096 packets
    int L = p & 63;
    int idx = p >> 6;                        // h*8+nt
    int h = idx >> 3, nt = idx & 7;
    int n = nt*16 + (L & 15);
    int k0 = (L >> 4)*8;
    short8 v;
    #pragma unroll
    for (int j=0;j<8;j++){
        int k = k0 + j;
        v[j] = (k < 16) ? (short)f2bf(Wout[(h*16+k)*128 + n]) : (short)0;
    }
    *(short8*)&Woutp[(long)p*8] = v;
}

// ---------------------------------------------------------------------------
// Fused MFMA attention (R6/R8 best: 4 sites, 32 KB LDS, 77 us, 41% occ).
__global__ __launch_bounds__(256,5)
void k_attn_mfma(const float* __restrict__ X, const short* __restrict__ Winp,
                 const short* __restrict__ Woutp, const float* __restrict__ resid,
                 float* __restrict__ Y){
    __shared__ short lds[16000];             // 32,000 B
    const int XO=0;                          // X tile  [64][136]
    const int QO=8704;                       // Q plain [64][24]
    const int KO=10240;                      // K plain [64][24]
    const int VO=11776;                      // V^T     [16][72] (cols = m)
    const int PO=12928;                      // P plain [64][24]
    const int AOO=14464;                     // ao      [64][24]
    int tid = threadIdx.x;
    int w = tid >> 6, L = tid & 63;
    int quad = L >> 4, lm = L & 15;
    int b = blockIdx.x >> 8, tile = blockIdx.x & 255;
    int hw0 = tile * 4;
    int hw = hw0 + w;                        // this wave's site

    // phase 1: wave-local X rows w*16..w*16+15 (site w), fp32->bf16
    {
        int cq = L & 31, rh = L >> 5;
        for (int p=0; p<8; p++){
            int m = w*16 + p*2 + rh;
            int s = m & 15;
            float4 v = *(const float4*)&X[((((long)b*16 + s)*1024) + hw)*128 + cq*4];
            short4v hv;
            hv[0]=(short)f2bf(v.x); hv[1]=(short)f2bf(v.y);
            hv[2]=(short)f2bf(v.z); hv[3]=(short)f2bf(v.w);
            *(short4v*)&lds[XO + m*136 + cq*4] = hv;
        }
    }

    floatx4 Oa[8];
    #pragma unroll
    for (int nt=0;nt<8;nt++) Oa[nt] = (floatx4){0.f,0.f,0.f,0.f};

    const floatx4 zc = (floatx4){0.f,0.f,0.f,0.f};
    const short8 z8 = {0,0,0,0,0,0,0,0};
    int m0 = w*16;

    for (int h=0; h<8; h++){
        // ---- phase 2: QKV GEMM for n-tiles {3h, 3h+1, 3h+2} = q,k,v of head h
        floatx4 qacc[3];
        #pragma unroll
        for (int t=0;t<3;t++) qacc[t] = zc;
        #pragma unroll
        for (int kc=0;kc<4;kc++){
            short8 af = *(const short8*)&lds[XO + (m0+lm)*136 + kc*32 + quad*8];
            #pragma unroll
            for (int t=0;t<3;t++){
                int nt = 3*h + t;
                short8 bf = *(const short8*)&Winp[(long)((nt*4+kc)*64 + L)*8];
                qacc[t] = __builtin_amdgcn_mfma_f32_16x16x32_bf16(af, bf, qacc[t], 0,0,0);
            }
        }
        // epilogue: Q,K -> plain [m][d]; V -> V^T [d][m]
        #pragma unroll
        for (int r=0;r<4;r++){
            lds[QO + (m0+quad*4+r)*24 + lm] = (short)f2bf(qacc[0][r]);
            lds[KO + (m0+quad*4+r)*24 + lm] = (short)f2bf(qacc[1][r]);
        }
        {
            short4v vv;
            #pragma unroll
            for (int r=0;r<4;r++) vv[r] = (short)f2bf(qacc[2][r]);
            *(short4v*)&lds[VO + lm*72 + m0 + quad*4] = vv;
        }

        // ---- phase 3: per-site scores -> softmax -> PV ----
        {
            short8 qf = z8, kf = z8;
            if (quad < 2){
                qf = *(const short8*)&lds[QO + (m0+lm)*24 + quad*8];
                kf = *(const short8*)&lds[KO + (m0+lm)*24 + quad*8];
            }
            floatx4 scv = __builtin_amdgcn_mfma_f32_16x16x32_bf16(qf, kf, zc, 0,0,0);
            float pv[4], mr[4];
            #pragma unroll
            for (int r=0;r<4;r++){
                int si = quad*4 + r;
                pv[r] = scv[r]*0.25f + (lm <= si ? 1.0f : -1000.0f);
                mr[r] = pv[r];
            }
            #pragma unroll
            for (int d=1; d<16; d<<=1)
                #pragma unroll
                for (int r=0;r<4;r++) mr[r] = fmaxf(mr[r], __shfl_xor(mr[r], d));
            float ex[4], sm[4];
            #pragma unroll
            for (int r=0;r<4;r++){ ex[r] = __expf(pv[r]-mr[r]); sm[r] = ex[r]; }
            #pragma unroll
            for (int d=1; d<16; d<<=1)
                #pragma unroll
                for (int r=0;r<4;r++) sm[r] += __shfl_xor(sm[r], d);
            #pragma unroll
            for (int r=0;r<4;r++)
                lds[PO + (m0+quad*4+r)*24 + lm] = (short)f2bf(ex[r]/sm[r]);

            short8 pf = z8, vf = z8;
            if (quad < 2){
                pf = *(const short8*)&lds[PO + (m0+lm)*24 + quad*8];
                vf = *(const short8*)&lds[VO + lm*72 + m0 + quad*8];
            }
            floatx4 aov = __builtin_amdgcn_mfma_f32_16x16x32_bf16(pf, vf, zc, 0,0,0);
            #pragma unroll
            for (int r=0;r<4;r++)
                lds[AOO + (m0+quad*4+r)*24 + lm] = (short)f2bf(aov[r]);
        }

        // ---- phase 4: O += ao_h @ Wout[h-rows] ----
        {
            short8 aof = z8;
            if (quad < 2)
                aof = *(const short8*)&lds[AOO + (m0+lm)*24 + quad*8];
            #pragma unroll
            for (int nt=0;nt<8;nt++){
                short8 wf = *(const short8*)&Woutp[(long)((h*8+nt)*64 + L)*8];
                Oa[nt] = __builtin_amdgcn_mfma_f32_16x16x32_bf16(aof, wf, Oa[nt], 0,0,0);
            }
        }
    }

    // epilogue: O + residual -> Y (in place over X rows this block loaded)
    #pragma unroll
    for (int nt=0;nt<8;nt++){
        int n = nt*16 + lm;
        #pragma unroll
        for (int r=0;r<4;r++){
            int s = quad*4 + r;
            long addr = (((long)b*16 + s)*1024 + hw)*128 + n;
            Y[addr] = Oa[nt][r] + resid[addr];
        }
    }
}

// ---------------------------------------------------------------------------
// Weights -> B-fragment packets, bf16 (conv GEMM).
__global__ __launch_bounds__(256)
void k_pack_w(const float* __restrict__ ck, short* __restrict__ Bp){
    int p = blockIdx.x*256 + threadIdx.x;     // 147456 exact
    int L = p & 63;
    int nt = (p >> 6) & 31;
    int c32 = (p >> 11) & 7;
    int tap = p >> 14;
    int oc = nt*16 + (L & 15);
    int kq = L >> 4;
    short8 v;
    #pragma unroll
    for (int j=0;j<8;j++){
        int ic = c32*32 + kq*8 + j;
        v[j] = (short)f2bf(ck[(oc*256+ic)*9 + tap]);
    }
    *(short8*)&Bp[(long)p*8] = v;
}

// ---------------------------------------------------------------------------
// Pack X slice s (fp32) -> bf16 x-half of xh[row][0:128]; zero h-half at s==0
// (used once for s=0; the fused conv+lstm kernel packs slices 1..15 inline)
__global__ __launch_bounds__(256)
void k_pack_x(const float* __restrict__ X, short* __restrict__ xh, int s, int zero_h){
    int idx = blockIdx.x*256 + threadIdx.x;   // 131072
    int row = idx >> 4;
    int ch = (idx & 15) * 8;
    int b = row >> 10, hw = row & 1023;
    const float* src = X + (((long)(b*16+s)*1024 + hw)*128 + ch);
    float4 a = *(const float4*)src;
    float4 c = *(const float4*)(src+4);
    short8 v;
    v[0]=(short)f2bf(a.x); v[1]=(short)f2bf(a.y); v[2]=(short)f2bf(a.z); v[3]=(short)f2bf(a.w);
    v[4]=(short)f2bf(c.x); v[5]=(short)f2bf(c.y); v[6]=(short)f2bf(c.z); v[7]=(short)f2bf(c.w);
    *(short8*)&xh[(long)row*256 + ch] = v;
    if (zero_h){
        short8 z = {0,0,0,0,0,0,0,0};
        *(short8*)&xh[(long)row*256 + 128 + ch] = z;
    }
}

// ---------------------------------------------------------------------------
// Fused implicit-im2col conv GEMM + LSTM pointwise (R10).
// R9's fusion regressed because the epilogue used per-lane SCALAR global
// accesses (2-byte xh stores, scalar cbuf/X). R10 keeps the fusion (no gbuf,
// 16 dispatches/scan) but routes gates through LDS to restore vectorization:
// K-loop -> barrier -> scatter gates to Gs[row][ch][gate] (f32, c-group
// stride 33 spreads b128 reads across bank groups) -> barrier -> each thread
// does the pointwise on 4-channel groups with float4 cbuf/X and ushort4 xh.
// Gate values, accumulation order (tap,sic,c2), and pointwise math are
// bit-identical to R8 -> absmax unchanged.
__global__ __launch_bounds__(512,2)
void k_conv_lstm(const short* __restrict__ xh_in, const short* __restrict__ Bp,
                 float* __restrict__ cbuf, float* __restrict__ X,
                 short* __restrict__ xh_out, int s){
    __shared__ short As[6*34*264];           // 107,712 B (Gs reuse: 67,584 B)
    int tid = threadIdx.x;
    int Nblk = blockIdx.x & 3, g = blockIdx.x >> 2;      // g 0..63
    int b = g >> 3, y0 = (g & 7)*4;
    int w = tid >> 6, L = tid & 63;
    int quad = L >> 4, lm = L & 15;
    int wm = w >> 1, wn = w & 1;             // wave -> (m-row, n-half)

    // ---- stage A halo: rows y0-1..y0+4, x -1..32, ch 0..255 (zero-padded)
    const short8 z8 = {0,0,0,0,0,0,0,0};
    {
        short8 vs[13];
        #pragma unroll
        for (int i=0; i<13; i++){
            int pidx = i*512 + tid;
            short8 v = z8;
            if (pidx < 6528){
                int cb  = pidx & 31;             // 8-ch granule
                int pos = pidx >> 5;             // row*34 + xp
                int row = pos / 34;
                int xp  = pos - row*34;
                int yy = y0 - 1 + row, xx = xp - 1;
                if (yy>=0 && yy<32 && xx>=0 && xx<32)
                    v = *(const short8*)&xh_in[(((long)(b*32+yy)*32+xx)<<8) + cb*8];
            }
            vs[i] = v;
        }
        #pragma unroll
        for (int i=0; i<13; i++){
            int pidx = i*512 + tid;
            if (pidx < 6528){
                int cb  = pidx & 31;
                int pos = pidx >> 5;
                *(short8*)&As[pos*264 + cb*8] = vs[i];
            }
        }
    }
    __syncthreads();

    floatx4 acc[2][4];
    #pragma unroll
    for (int mtl=0;mtl<2;mtl++)
        #pragma unroll
        for (int q=0;q<4;q++)
            acc[mtl][q] = (floatx4){0.f,0.f,0.f,0.f};

    const short8* Bp8 = (const short8*)Bp;

    for (int tap=0; tap<9; tap++){
        int dy = tap/3 - 1, dx = tap - (tap/3)*3 - 1;
        int abase[2];
        #pragma unroll
        for (int mtl=0;mtl<2;mtl++){
            int x = mtl*16 + lm;
            abase[mtl] = (((wm+dy+1)*34) + x + dx + 1)*264 + quad*8;
        }
        #pragma unroll
        for (int sic=0; sic<4; sic++){
            #pragma unroll
            for (int c2=0; c2<2; c2++){
                short8 bfr[4];
                #pragma unroll
                for (int q=0;q<4;q++)
                    bfr[q] = Bp8[((tap*8 + sic*2 + c2)*32 + q*8 + Nblk*2 + wn)*64 + L];
                #pragma unroll
                for (int mtl=0;mtl<2;mtl++){
                    short8 afr = *(const short8*)&As[abase[mtl] + sic*64 + c2*32];
                    #pragma unroll
                    for (int q=0;q<4;q++)
                        acc[mtl][q] = __builtin_amdgcn_mfma_f32_16x16x32_bf16(afr, bfr[q], acc[mtl][q], 0,0,0);
                }
            }
        }
    }

    // ---- gates -> LDS [row_local][c(stride 33)][gate] ----
    __syncthreads();                         // all waves done reading As
    float* Gs = (float*)As;                  // 128*33*4 floats = 67,584 B
    {
        int c = wn*16 + lm;                  // 0..31 within this block's 32 ch
        #pragma unroll
        for (int mtl=0;mtl<2;mtl++)
            #pragma unroll
            for (int r=0;r<4;r++){
                int row = wm*32 + mtl*16 + quad*4 + r;
                #pragma unroll
                for (int q=0;q<4;q++)
                    Gs[(row*33 + c)*4 + q] = acc[mtl][q][r];
            }
    }
    __syncthreads();

    // ---- vectorized LSTM pointwise: 2 groups of 4 channels per thread ----
    #pragma unroll
    for (int grp=0; grp<2; grp++){
        int gid = grp*512 + tid;             // 1024 groups = 128 rows x 8 c-grps
        int row_local = gid >> 3;
        int c0 = (gid & 7)*4;
        long row = (long)g*128 + row_local;  // = b*1024 + hw
        int ch = Nblk*32 + c0;
        floatx4 gv[4];
        #pragma unroll
        for (int j=0;j<4;j++)
            gv[j] = *(const floatx4*)&Gs[(row_local*33 + c0 + j)*4];
        float co[4] = {0.f,0.f,0.f,0.f};
        if (s != 0){
            float4 cv = *(const float4*)&cbuf[row*128 + ch];
            co[0]=cv.x; co[1]=cv.y; co[2]=cv.z; co[3]=cv.w;
        }
        float cn[4], hn[4];
        #pragma unroll
        for (int j=0;j<4;j++){
            cn[j] = sigf(gv[j][1])*co[j] + sigf(gv[j][0])*tanh_fast(gv[j][3]);
            hn[j] = sigf(gv[j][2])*tanh_fast(cn[j]);
        }
        *(float4*)&cbuf[row*128 + ch] = make_float4(cn[0],cn[1],cn[2],cn[3]);
        int b2 = (int)(row >> 10), hw = (int)(row & 1023);
        long xoff = (((long)(b2*16+s)*1024 + hw)*128) + ch;
        *(float4*)&X[xoff] = make_float4(hn[0],hn[1],hn[2],hn[3]);
        ushort4 hv;
        hv.x=f2bf(hn[0]); hv.y=f2bf(hn[1]); hv.z=f2bf(hn[2]); hv.w=f2bf(hn[3]);
        *(ushort4*)&xh_out[row*256 + 128 + ch] = hv;
        if (s < 15){
            long x2 = (((long)(b2*16+s+1)*1024 + hw)*128) + ch;
            float4 xv = *(const float4*)&X[x2];
            ushort4 xb;
            xb.x=f2bf(xv.x); xb.y=f2bf(xv.y); xb.z=f2bf(xv.z); xb.w=f2bf(xv.w);
            *(ushort4*)&xh_out[row*256 + ch] = xb;
        }
    }
}

// ---------------------------------------------------------------------------
extern "C" void kernel_launch(void* const* d_in, const int* in_sizes, int n_in,
                              void* d_out, int out_size, void* d_ws, size_t ws_size,
                              hipStream_t stream){
    const float* inputs = (const float*)d_in[0];
    const float* Wp     = (const float*)d_in[1];
    const float* gamma  = (const float*)d_in[2];
    const float* beta   = (const float*)d_in[3];
    const float* Win    = (const float*)d_in[4];
    const float* Wout   = (const float*)d_in[5];
    const float* ck     = (const float*)d_in[6];
    float* X = (float*)d_out;

    char* ws = (char*)d_ws;
    const size_t szB    = 147456ull*16;        // 2,359,296
    const size_t szXH   = 8192ull*256*2;       // 4,194,304 (each buffer)
    const size_t szC    = 8192ull*128*4;       // 4,194,304
    const size_t szWin  = 6144ull*16;          //    98,304
    const size_t szWout = 4096ull*16;          //    65,536
    short* Bp    = (short*)(ws);
    short* xh0   = (short*)(ws + szB);
    float* cbuf  = (float*)(ws + szB + szXH);
    short* Winp  = (short*)(ws + szB + szXH + szC);
    short* Woutp = (short*)(ws + szB + szXH + szC + szWin);
    short* xh1   = (short*)(ws + szB + szXH + szC + szWin + szWout);
    short* Wprojp= (short*)(ws + szB + szXH + szC + szWin + szWout + szXH);

    k_pack_w<<<576, 256, 0, stream>>>(ck, Bp);
    k_pack_win<<<24, 256, 0, stream>>>(Win, Winp);
    k_pack_wout<<<16, 256, 0, stream>>>(Wout, Woutp);
    k_pack_wproj<<<24, 256, 0, stream>>>(Wp, Wprojp);
    k_proj_ln_mfma<<<NTOK/64, 256, 0, stream>>>(inputs, Wprojp, gamma, beta, X);
    k_attn_mfma<<<2048, 256, 0, stream>>>(X, Winp, Woutp, inputs, X);  // in-place
    k_pack_x<<<512, 256, 0, stream>>>(X, xh0, 0, 1);

    for (int s=0; s<16; s++){
        const short* xin = (s & 1) ? xh1 : xh0;
        short*       xout= (s & 1) ? xh0 : xh1;
        k_conv_lstm<<<256, 512, 0, stream>>>(xin, Bp, cbuf, X, xout, s);
    }
}

// Round 11
// 870.920 us; speedup vs baseline: 1.0793x; 1.0652x over previous
//
#include <hip/hip_runtime.h>
#include <math.h>

#define B_  8
#define S_  16
#define H_  32
#define W_  32
#define E_  128
#define NH_ 8
#define HD_ 16
#define HW_ (H_*W_)            // 1024
#define NTOK (B_*S_*H_*W_)     // 131072

typedef __attribute__((ext_vector_type(8))) short short8;
typedef __attribute__((ext_vector_type(4))) short short4v;
typedef __attribute__((ext_vector_type(4))) float floatx4;

__device__ __forceinline__ float sigf(float x){
    return 1.f/(1.f+__expf(-x));
}
__device__ __forceinline__ float tanh_fast(float x){
    x = fminf(fmaxf(x, -15.f), 15.f);
    float e = __expf(2.f*x);
    return (e-1.f)/(e+1.f);
}
__device__ __forceinline__ unsigned short f2bf(float f){
    unsigned int u = __float_as_uint(f);
    u = (u + 0x7fffu + ((u >> 16) & 1u)) >> 16;   // RNE
    return (unsigned short)u;
}
__device__ __forceinline__ float bf2f(unsigned short h){
    return __uint_as_float(((unsigned int)h) << 16);
}

__device__ __forceinline__ void st_gate(float* p, float v){ *p = v; }
__device__ __forceinline__ void st_gate(unsigned short* p, float v){ *p = f2bf(v); }
__device__ __forceinline__ void load_gate(const float* p, float* o){
    float4 v = *(const float4*)p; o[0]=v.x; o[1]=v.y; o[2]=v.z; o[3]=v.w;
}
__device__ __forceinline__ void load_gate(const unsigned short* p, float* o){
    ushort4 v = *(const ushort4*)p;
    o[0]=bf2f(v.x); o[1]=bf2f(v.y); o[2]=bf2f(v.z); o[3]=bf2f(v.w);
}

// ---------------------------------------------------------------------------
// W_proj (128x128 fp32) -> split-bf16 B' fragments for K=384 GEMM.
__global__ __launch_bounds__(256)
void k_pack_wproj(const float* __restrict__ Wp, short* __restrict__ Wpp){
    int p = blockIdx.x*256 + threadIdx.x;    // 6144 packets
    int L = p & 63;
    int idx = p >> 6;                        // nt*12 + kb
    int nt = idx / 12, kb = idx - nt*12;
    int n = nt*16 + (L & 15);
    int kr = (kb & 3)*32 + (L >> 4)*8;
    bool lo = (kb >= 8);
    short8 v;
    #pragma unroll
    for (int j=0;j<8;j++){
        float wv = Wp[(kr+j)*128 + n];
        unsigned short h = f2bf(wv);
        v[j] = lo ? (short)f2bf(wv - bf2f(h)) : (short)h;
    }
    *(short8*)&Wpp[(long)p*8] = v;
}

// ---------------------------------------------------------------------------
// X = LayerNorm(silu(inputs @ W_proj)) via split-bf16 MFMA (fp32-accurate).
// Wave = 4 m-tiles x 2 n-tiles (B per wave 24 KB); LN row-sums cross waves
// via LDS red[] + barrier.
__global__ __launch_bounds__(256,4)
void k_proj_ln_mfma(const float* __restrict__ in, const short* __restrict__ Wpp,
                    const float* __restrict__ gamma, const float* __restrict__ beta,
                    float* __restrict__ X){
    __shared__ short As[64*264];             // 33,792 B
    __shared__ float red[4][64][2];          //  2,048 B
    int tid = threadIdx.x;
    int w = tid >> 6, L = tid & 63;
    int quad = L >> 4, lm = L & 15;
    long r0 = (long)blockIdx.x * 64;

    // stage: 64 rows x 128 f32 -> split bf16 (coalesced float4 loads)
    {
        int c = (tid & 31)*4;
        int rbase = tid >> 5;
        #pragma unroll
        for (int rr=0; rr<8; rr++){
            int r = rr*8 + rbase;
            float4 v = *(const float4*)&in[(r0 + r)*128 + c];
            short4v hv, lv;
            unsigned short h;
            h = f2bf(v.x); hv[0]=(short)h; lv[0]=(short)f2bf(v.x - bf2f(h));
            h = f2bf(v.y); hv[1]=(short)h; lv[1]=(short)f2bf(v.y - bf2f(h));
            h = f2bf(v.z); hv[2]=(short)h; lv[2]=(short)f2bf(v.z - bf2f(h));
            h = f2bf(v.w); hv[3]=(short)h; lv[3]=(short)f2bf(v.w - bf2f(h));
            *(short4v*)&As[r*264 + c] = hv;
            *(short4v*)&As[r*264 + 128 + c] = lv;
        }
    }
    __syncthreads();

    floatx4 acc[4][2];
    #pragma unroll
    for (int mtl=0;mtl<4;mtl++)
        #pragma unroll
        for (int nti=0;nti<2;nti++)
            acc[mtl][nti] = (floatx4){0.f,0.f,0.f,0.f};
    const short8* Bp8 = (const short8*)Wpp;
    #pragma unroll
    for (int kb=0; kb<12; kb++){
        int off = (kb<4) ? kb*32 : ((kb<8) ? 128+(kb-4)*32 : (kb-8)*32);
        short8 af[4];
        #pragma unroll
        for (int mtl=0;mtl<4;mtl++)
            af[mtl] = *(const short8*)&As[(mtl*16+lm)*264 + off + quad*8];
        #pragma unroll
        for (int nti=0;nti<2;nti++){
            short8 bf = Bp8[((2*w+nti)*12+kb)*64 + L];
            #pragma unroll
            for (int mtl=0;mtl<4;mtl++)
                acc[mtl][nti] = __builtin_amdgcn_mfma_f32_16x16x32_bf16(af[mtl], bf, acc[mtl][nti], 0,0,0);
        }
    }

    // fused silu + LayerNorm epilogue (cross-wave row reduction).
    #pragma unroll
    for (int mtl=0;mtl<4;mtl++){
        float p1[4]={0,0,0,0}, p2[4]={0,0,0,0};
        #pragma unroll
        for (int nti=0;nti<2;nti++)
            #pragma unroll
            for (int r=0;r<4;r++){
                float a = acc[mtl][nti][r];
                float si = a*sigf(a);             // silu
                acc[mtl][nti][r] = si;
                p1[r] += si; p2[r] += si*si;
            }
        #pragma unroll
        for (int d=1; d<16; d<<=1)
            #pragma unroll
            for (int r=0;r<4;r++){
                p1[r] += __shfl_xor(p1[r], d);
                p2[r] += __shfl_xor(p2[r], d);
            }
        if (lm == 0){
            #pragma unroll
            for (int r=0;r<4;r++){
                int row = mtl*16 + quad*4 + r;
                red[w][row][0] = p1[r];
                red[w][row][1] = p2[r];
            }
        }
    }
    __syncthreads();
    float g[2], bb[2];
    #pragma unroll
    for (int nti=0;nti<2;nti++){
        g[nti]  = gamma[(2*w+nti)*16 + lm];
        bb[nti] = beta [(2*w+nti)*16 + lm];
    }
    #pragma unroll
    for (int mtl=0;mtl<4;mtl++){
        #pragma unroll
        for (int r=0;r<4;r++){
            int row = mtl*16 + quad*4 + r;
            float s1 = red[0][row][0] + red[1][row][0] + red[2][row][0] + red[3][row][0];
            float s2 = red[0][row][1] + red[1][row][1] + red[2][row][1] + red[3][row][1];
            float mu  = s1 * (1.f/128.f);
            float var = s2 * (1.f/128.f) - mu*mu;
            float rs  = rsqrtf(var + 1e-5f);
            #pragma unroll
            for (int nti=0;nti<2;nti++)
                X[(r0+row)*128 + (2*w+nti)*16 + lm] = (acc[mtl][nti][r]-mu)*rs*g[nti] + bb[nti];
        }
    }
}

// ---------------------------------------------------------------------------
// W_in (128x384) -> bf16 B-fragment packets.
__global__ __launch_bounds__(256)
void k_pack_win(const float* __restrict__ Win, short* __restrict__ Winp){
    int p = blockIdx.x*256 + threadIdx.x;    // 6144 packets
    int L = p & 63;
    int idx = p >> 6;                        // nt*4+kc
    int nt = idx >> 2, kc = idx & 3;
    int n = nt*16 + (L & 15);
    int k0 = kc*32 + (L >> 4)*8;
    short8 v;
    #pragma unroll
    for (int j=0;j<8;j++) v[j] = (short)f2bf(Win[(k0+j)*384 + n]);
    *(short8*)&Winp[(long)p*8] = v;
}

// ---------------------------------------------------------------------------
// W_out (128x128) -> per-head zero-padded B packets.
__global__ __launch_bounds__(256)
void k_pack_wout(const float* __restrict__ Wout, short* __restrict__ Woutp){
    int p = blockIdx.x*256 + threadIdx.x;    // 4096 packets
    int L = p & 63;
    int idx = p >> 6;                        // h*8+nt
    int h = idx >> 3, nt = idx & 7;
    int n = nt*16 + (L & 15);
    int k0 = (L >> 4)*8;
    short8 v;
    #pragma unroll
    for (int j=0;j<8;j++){
        int k = k0 + j;
        v[j] = (k < 16) ? (short)f2bf(Wout[(h*16+k)*128 + n]) : (short)0;
    }
    *(short8*)&Woutp[(long)p*8] = v;
}

// ---------------------------------------------------------------------------
// Fused MFMA attention (R6/R8 structure: 4 sites, 32 KB LDS).
// R11 softmax shortening: (i) no max-subtract — scores bounded (LN'd inputs,
// HD=16, |score|<~10), exp can't overflow; masked lanes give exp(-999)=0.
// (ii) P stored UNNORMALIZED; the sum-shuffle rounds overlap with the PV
// LDS reads/MFMA, and aov rows are divided by the sum afterwards (same math,
// rounding-level change only).
__global__ __launch_bounds__(256,5)
void k_attn_mfma(const float* __restrict__ X, const short* __restrict__ Winp,
                 const short* __restrict__ Woutp, const float* __restrict__ resid,
                 float* __restrict__ Y){
    __shared__ short lds[16000];             // 32,000 B
    const int XO=0;                          // X tile  [64][136]
    const int QO=8704;                       // Q plain [64][24]
    const int KO=10240;                      // K plain [64][24]
    const int VO=11776;                      // V^T     [16][72] (cols = m)
    const int PO=12928;                      // P plain [64][24]
    const int AOO=14464;                     // ao      [64][24]
    int tid = threadIdx.x;
    int w = tid >> 6, L = tid & 63;
    int quad = L >> 4, lm = L & 15;
    int b = blockIdx.x >> 8, tile = blockIdx.x & 255;
    int hw0 = tile * 4;
    int hw = hw0 + w;                        // this wave's site

    // phase 1: wave-local X rows w*16..w*16+15 (site w), fp32->bf16
    {
        int cq = L & 31, rh = L >> 5;
        for (int p=0; p<8; p++){
            int m = w*16 + p*2 + rh;
            int s = m & 15;
            float4 v = *(const float4*)&X[((((long)b*16 + s)*1024) + hw)*128 + cq*4];
            short4v hv;
            hv[0]=(short)f2bf(v.x); hv[1]=(short)f2bf(v.y);
            hv[2]=(short)f2bf(v.z); hv[3]=(short)f2bf(v.w);
            *(short4v*)&lds[XO + m*136 + cq*4] = hv;
        }
    }

    floatx4 Oa[8];
    #pragma unroll
    for (int nt=0;nt<8;nt++) Oa[nt] = (floatx4){0.f,0.f,0.f,0.f};

    const floatx4 zc = (floatx4){0.f,0.f,0.f,0.f};
    const short8 z8 = {0,0,0,0,0,0,0,0};
    int m0 = w*16;

    for (int h=0; h<8; h++){
        // ---- phase 2: QKV GEMM for n-tiles {3h, 3h+1, 3h+2} = q,k,v of head h
        floatx4 qacc[3];
        #pragma unroll
        for (int t=0;t<3;t++) qacc[t] = zc;
        #pragma unroll
        for (int kc=0;kc<4;kc++){
            short8 af = *(const short8*)&lds[XO + (m0+lm)*136 + kc*32 + quad*8];
            #pragma unroll
            for (int t=0;t<3;t++){
                int nt = 3*h + t;
                short8 bf = *(const short8*)&Winp[(long)((nt*4+kc)*64 + L)*8];
                qacc[t] = __builtin_amdgcn_mfma_f32_16x16x32_bf16(af, bf, qacc[t], 0,0,0);
            }
        }
        // epilogue: Q,K -> plain [m][d]; V -> V^T [d][m]
        #pragma unroll
        for (int r=0;r<4;r++){
            lds[QO + (m0+quad*4+r)*24 + lm] = (short)f2bf(qacc[0][r]);
            lds[KO + (m0+quad*4+r)*24 + lm] = (short)f2bf(qacc[1][r]);
        }
        {
            short4v vv;
            #pragma unroll
            for (int r=0;r<4;r++) vv[r] = (short)f2bf(qacc[2][r]);
            *(short4v*)&lds[VO + lm*72 + m0 + quad*4] = vv;
        }

        // ---- phase 3: scores -> exp (no max-subtract) -> PV -> late normalize
        {
            short8 qf = z8, kf = z8;
            if (quad < 2){
                qf = *(const short8*)&lds[QO + (m0+lm)*24 + quad*8];
                kf = *(const short8*)&lds[KO + (m0+lm)*24 + quad*8];
            }
            floatx4 scv = __builtin_amdgcn_mfma_f32_16x16x32_bf16(qf, kf, zc, 0,0,0);
            float sm[4];
            #pragma unroll
            for (int r=0;r<4;r++){
                int si = quad*4 + r;
                float pv = scv[r]*0.25f + (lm <= si ? 1.0f : -1000.0f);
                float ex = __expf(pv);          // masked -> exp(-999) = 0
                sm[r] = ex;
                lds[PO + (m0+quad*4+r)*24 + lm] = (short)f2bf(ex);
            }

            short8 pf = z8, vf = z8;
            if (quad < 2){
                pf = *(const short8*)&lds[PO + (m0+lm)*24 + quad*8];
                vf = *(const short8*)&lds[VO + lm*72 + m0 + quad*8];
            }
            floatx4 aov = __builtin_amdgcn_mfma_f32_16x16x32_bf16(pf, vf, zc, 0,0,0);

            // sum reduction (overlaps PV above — no dependency)
            #pragma unroll
            for (int d=1; d<16; d<<=1)
                #pragma unroll
                for (int r=0;r<4;r++) sm[r] += __shfl_xor(sm[r], d);
            #pragma unroll
            for (int r=0;r<4;r++){
                float inv = __fdividef(1.0f, sm[r]);
                lds[AOO + (m0+quad*4+r)*24 + lm] = (short)f2bf(aov[r]*inv);
            }
        }

        // ---- phase 4: O += ao_h @ Wout[h-rows] ----
        {
            short8 aof = z8;
            if (quad < 2)
                aof = *(const short8*)&lds[AOO + (m0+lm)*24 + quad*8];
            #pragma unroll
            for (int nt=0;nt<8;nt++){
                short8 wf = *(const short8*)&Woutp[(long)((h*8+nt)*64 + L)*8];
                Oa[nt] = __builtin_amdgcn_mfma_f32_16x16x32_bf16(aof, wf, Oa[nt], 0,0,0);
            }
        }
    }

    // epilogue: O + residual -> Y (in place over X rows this block loaded)
    #pragma unroll
    for (int nt=0;nt<8;nt++){
        int n = nt*16 + lm;
        #pragma unroll
        for (int r=0;r<4;r++){
            int s = quad*4 + r;
            long addr = (((long)b*16 + s)*1024 + hw)*128 + n;
            Y[addr] = Oa[nt][r] + resid[addr];
        }
    }
}

// ---------------------------------------------------------------------------
// Weights -> B-fragment packets, bf16 (conv GEMM).
__global__ __launch_bounds__(256)
void k_pack_w(const float* __restrict__ ck, short* __restrict__ Bp){
    int p = blockIdx.x*256 + threadIdx.x;     // 147456 exact
    int L = p & 63;
    int nt = (p >> 6) & 31;
    int c32 = (p >> 11) & 7;
    int tap = p >> 14;
    int oc = nt*16 + (L & 15);
    int kq = L >> 4;
    short8 v;
    #pragma unroll
    for (int j=0;j<8;j++){
        int ic = c32*32 + kq*8 + j;
        v[j] = (short)f2bf(ck[(oc*256+ic)*9 + tap]);
    }
    *(short8*)&Bp[(long)p*8] = v;
}

// ---------------------------------------------------------------------------
// Pack X slice s (fp32) -> bf16 x-half of xh[row][0:128]; zero h-half at s==0
__global__ __launch_bounds__(256)
void k_pack_x(const float* __restrict__ X, short* __restrict__ xh, int s, int zero_h){
    int idx = blockIdx.x*256 + threadIdx.x;   // 131072
    int row = idx >> 4;
    int ch = (idx & 15) * 8;
    int b = row >> 10, hw = row & 1023;
    const float* src = X + (((long)(b*16+s)*1024 + hw)*128 + ch);
    float4 a = *(const float4*)src;
    float4 c = *(const float4*)(src+4);
    short8 v;
    v[0]=(short)f2bf(a.x); v[1]=(short)f2bf(a.y); v[2]=(short)f2bf(a.z); v[3]=(short)f2bf(a.w);
    v[4]=(short)f2bf(c.x); v[5]=(short)f2bf(c.y); v[6]=(short)f2bf(c.z); v[7]=(short)f2bf(c.w);
    *(short8*)&xh[(long)row*256 + ch] = v;
    if (zero_h){
        short8 z = {0,0,0,0,0,0,0,0};
        *(short8*)&xh[(long)row*256 + 128 + ch] = z;
    }
}

// ---------------------------------------------------------------------------
// Implicit-im2col MFMA GEMM: gates[8192][512] = patches(xh) @ W.
// R11: wave map flipped to wm=w&1 (M-half), wn=w>>1 (n-pair); wave =
// 4 m-tiles x 2 n-tiles. R8's map (wm 4 values) had every B packet fetched
// by 4 waves -> ~74 MB/XCD L2 requests (~17 us, the binder). New map halves
// B-redundancy (B ~8.6 us) for 2x A-LDS reads (~11.5 us) -> lower max.
// Everything else R8: Mtile 128, halo staged once, barrier-free K-loop,
// Nblk=blockIdx&3 XCD-aligned. Per-output K-order (tap,sic,c2) unchanged
// -> bit-identical gbuf.
template<typename GT>
__global__ __launch_bounds__(512,2)
void k_conv_mfma(const short* __restrict__ xh, const short* __restrict__ Bp,
                 GT* __restrict__ gbuf){
    __shared__ short As[6*34*264];           // 107,712 B
    int tid = threadIdx.x;
    int Nblk = blockIdx.x & 3, g = blockIdx.x >> 2;      // g 0..63
    int b = g >> 3, y0 = (g & 7)*4;
    int w = tid >> 6, L = tid & 63;
    int quad = L >> 4, lm = L & 15;
    int wm = w & 1, wn = w >> 1;             // wave -> (m-half, n-pair)
    int ntg = Nblk*8 + wn*2;                 // first of this wave's 2 n-tiles

    // ---- stage A halo: rows y0-1..y0+4, x -1..32, ch 0..255 (zero-padded)
    const short8 z8 = {0,0,0,0,0,0,0,0};
    {
        short8 vs[13];
        #pragma unroll
        for (int i=0; i<13; i++){
            int pidx = i*512 + tid;
            short8 v = z8;
            if (pidx < 6528){
                int cb  = pidx & 31;             // 8-ch granule
                int pos = pidx >> 5;             // row*34 + xp
                int row = pos / 34;
                int xp  = pos - row*34;
                int yy = y0 - 1 + row, xx = xp - 1;
                if (yy>=0 && yy<32 && xx>=0 && xx<32)
                    v = *(const short8*)&xh[(((long)(b*32+yy)*32+xx)<<8) + cb*8];
            }
            vs[i] = v;
        }
        #pragma unroll
        for (int i=0; i<13; i++){
            int pidx = i*512 + tid;
            if (pidx < 6528){
                int cb  = pidx & 31;
                int pos = pidx >> 5;
                *(short8*)&As[pos*264 + cb*8] = vs[i];
            }
        }
    }
    __syncthreads();

    floatx4 acc[4][2];
    #pragma unroll
    for (int mtl=0;mtl<4;mtl++)
        #pragma unroll
        for (int nti=0;nti<2;nti++)
            acc[mtl][nti] = (floatx4){0.f,0.f,0.f,0.f};

    const short8* Bp8 = (const short8*)Bp;

    for (int tap=0; tap<9; tap++){
        int dy = tap/3 - 1, dx = tap - (tap/3)*3 - 1;
        // wave wm owns image rows wm*2..wm*2+1; m-tile mtl -> y_local =
        // wm*2 + (mtl>>1), x = (mtl&1)*16 + lm
        int abase[4];
        #pragma unroll
        for (int mtl=0;mtl<4;mtl++){
            int yl = wm*2 + (mtl>>1);
            int x  = (mtl&1)*16 + lm;
            abase[mtl] = (((yl+dy+1)*34) + x + dx + 1)*264 + quad*8;
        }
        #pragma unroll
        for (int sic=0; sic<4; sic++){
            #pragma unroll
            for (int c2=0; c2<2; c2++){
                short8 bfr[2];
                #pragma unroll
                for (int nti=0;nti<2;nti++)
                    bfr[nti] = Bp8[((tap*8 + sic*2 + c2)*32 + ntg + nti)*64 + L];
                #pragma unroll
                for (int mtl=0;mtl<4;mtl++){
                    short8 afr = *(const short8*)&As[abase[mtl] + sic*64 + c2*32];
                    #pragma unroll
                    for (int nti=0;nti<2;nti++)
                        acc[mtl][nti] = __builtin_amdgcn_mfma_f32_16x16x32_bf16(afr, bfr[nti], acc[mtl][nti], 0,0,0);
                }
            }
        }
    }

    #pragma unroll
    for (int mtl=0;mtl<4;mtl++){
        #pragma unroll
        for (int nti=0;nti<2;nti++){
            int n = Nblk*128 + (wn*2+nti)*16 + lm;
            #pragma unroll
            for (int r=0;r<4;r++){
                long row = (long)g*128 + wm*64 + mtl*16 + quad*4 + r;
                st_gate(&gbuf[row*512 + n], acc[mtl][nti][r]);
            }
        }
    }
}

// ---------------------------------------------------------------------------
// Fused LSTM pointwise + inline pack of next slice's x-half.
template<typename GT>
__global__ __launch_bounds__(256)
void k_lstm(const GT* __restrict__ gbuf, float* __restrict__ cbuf,
            float* __restrict__ X, short* __restrict__ xh, int s){
    int idx = blockIdx.x*256 + threadIdx.x;    // 262144
    int row = idx >> 5;
    int c4 = (idx & 31)*4;
    float gi[4], gf[4], go[4], gg[4];
    const GT* gp = gbuf + (long)row*512 + c4;
    load_gate(gp,       gi);
    load_gate(gp + 128, gf);
    load_gate(gp + 256, go);
    load_gate(gp + 384, gg);
    float co[4];
    if (s == 0){ co[0]=co[1]=co[2]=co[3]=0.f; }
    else {
        float4 cv = *(const float4*)&cbuf[(long)row*128 + c4];
        co[0]=cv.x; co[1]=cv.y; co[2]=cv.z; co[3]=cv.w;
    }
    float cn[4], hn[4];
    #pragma unroll
    for (int j=0;j<4;j++){
        cn[j] = sigf(gf[j])*co[j] + sigf(gi[j])*tanh_fast(gg[j]);
        hn[j] = sigf(go[j])*tanh_fast(cn[j]);
    }
    *(float4*)&cbuf[(long)row*128 + c4] = make_float4(cn[0],cn[1],cn[2],cn[3]);
    int b = row >> 10, hw = row & 1023;
    long xoff = (((long)(b*16+s)*1024 + hw)*128) + c4;
    *(float4*)&X[xoff] = make_float4(hn[0],hn[1],hn[2],hn[3]);
    ushort4 hv;
    hv.x = f2bf(hn[0]); hv.y = f2bf(hn[1]); hv.z = f2bf(hn[2]); hv.w = f2bf(hn[3]);
    *(ushort4*)&xh[(long)row*256 + 128 + c4] = hv;
    // pack next slice's x-half (attn output slice s+1 is untouched)
    if (s < 15){
        long x2 = (((long)(b*16+s+1)*1024 + hw)*128) + c4;
        float4 xv = *(const float4*)&X[x2];
        ushort4 xb;
        xb.x = f2bf(xv.x); xb.y = f2bf(xv.y); xb.z = f2bf(xv.z); xb.w = f2bf(xv.w);
        *(ushort4*)&xh[(long)row*256 + c4] = xb;
    }
}

// ---------------------------------------------------------------------------
extern "C" void kernel_launch(void* const* d_in, const int* in_sizes, int n_in,
                              void* d_out, int out_size, void* d_ws, size_t ws_size,
                              hipStream_t stream){
    const float* inputs = (const float*)d_in[0];
    const float* Wp     = (const float*)d_in[1];
    const float* gamma  = (const float*)d_in[2];
    const float* beta   = (const float*)d_in[3];
    const float* Win    = (const float*)d_in[4];
    const float* Wout   = (const float*)d_in[5];
    const float* ck     = (const float*)d_in[6];
    float* X = (float*)d_out;

    char* ws = (char*)d_ws;
    const size_t szB    = 147456ull*16;        // 2,359,296
    const size_t szXH   = 8192ull*256*2;       // 4,194,304
    const size_t szC    = 8192ull*128*4;       // 4,194,304
    const size_t szWin  = 6144ull*16;          //    98,304
    const size_t szWout = 4096ull*16;          //    65,536
    short* Bp    = (short*)(ws);
    short* xh    = (short*)(ws + szB);
    float* cbuf  = (float*)(ws + szB + szXH);
    short* Winp  = (short*)(ws + szB + szXH + szC);
    short* Woutp = (short*)(ws + szB + szXH + szC + szWin);
    char*  gch   =         ws + szB + szXH + szC + szWin + szWout;
    bool gate_f32 = ws_size >= (szB + szXH + szC + szWin + szWout + 8192ull*512*4);
    short* Wprojp = (short*)gch;   // aliases gbuf; consumed before first conv

    k_pack_w<<<576, 256, 0, stream>>>(ck, Bp);
    k_pack_win<<<24, 256, 0, stream>>>(Win, Winp);
    k_pack_wout<<<16, 256, 0, stream>>>(Wout, Woutp);
    k_pack_wproj<<<24, 256, 0, stream>>>(Wp, Wprojp);
    k_proj_ln_mfma<<<NTOK/64, 256, 0, stream>>>(inputs, Wprojp, gamma, beta, X);
    k_attn_mfma<<<2048, 256, 0, stream>>>(X, Winp, Woutp, inputs, X);  // in-place
    k_pack_x<<<512, 256, 0, stream>>>(X, xh, 0, 1);

    if (gate_f32){
        float* gbuf = (float*)gch;
        for (int s=0; s<16; s++){
            k_conv_mfma<float><<<256, 512, 0, stream>>>(xh, Bp, gbuf);
            k_lstm<float><<<1024, 256, 0, stream>>>(gbuf, cbuf, X, xh, s);
        }
    } else {
        unsigned short* gbuf = (unsigned short*)gch;
        for (int s=0; s<16; s++){
            k_conv_mfma<unsigned short><<<256, 512, 0, stream>>>(xh, Bp, gbuf);
            k_lstm<unsigned short><<<1024, 256, 0, stream>>>(gbuf, cbuf, X, xh, s);
        }
    }
}